// Round 4
// baseline (159.905 us; speedup 1.0000x reference)
//
#include <hip/hip_runtime.h>

#define INV_SQRT2 0.70710678118654752440f

// Original (non-reversed) analysis filter tables, exactly as in the reference.
// The synthesis filters are the time-reversed rows; we fold the reversal into
// the index:  out[2s+r] = sum_p ORIG[9 - r - 2p][ch] * x[(s+2-p) mod n]
__constant__ float c_first[2][10][2] = {
  { { 0.00000000000000f,  0.00000000000000f},
    {-0.08838834764832f, -0.01122679215254f},
    { 0.08838834764832f,  0.01122679215254f},
    { 0.69587998903400f,  0.08838834764832f},
    { 0.69587998903400f,  0.08838834764832f},
    { 0.08838834764832f, -0.69587998903400f},
    {-0.08838834764832f,  0.69587998903400f},
    { 0.01122679215254f, -0.08838834764832f},
    { 0.01122679215254f, -0.08838834764832f},
    { 0.00000000000000f,  0.00000000000000f} },
  { { 0.01122679215254f,  0.00000000000000f},
    { 0.01122679215254f,  0.00000000000000f},
    {-0.08838834764832f, -0.08838834764832f},
    { 0.08838834764832f, -0.08838834764832f},
    { 0.69587998903400f,  0.69587998903400f},
    { 0.69587998903400f, -0.69587998903400f},
    { 0.08838834764832f,  0.08838834764832f},
    {-0.08838834764832f,  0.08838834764832f},
    { 0.00000000000000f,  0.01122679215254f},
    { 0.00000000000000f, -0.01122679215254f} }
};

__constant__ float c_qshift[2][10][2] = {
  { { 0.03516384f,  0.00000000f},
    { 0.00000000f,  0.00000000f},
    {-0.08832942f, -0.11430184f},
    { 0.23389032f,  0.00000000f},
    { 0.76027237f,  0.58751830f},
    { 0.58751830f, -0.76027237f},
    { 0.00000000f,  0.23389032f},
    {-0.11430184f,  0.08832942f},
    { 0.00000000f,  0.00000000f},
    { 0.00000000f, -0.03516384f} },
  { { 0.00000000f, -0.03516384f},
    { 0.00000000f,  0.00000000f},
    {-0.11430184f,  0.08832942f},
    { 0.00000000f,  0.23389032f},
    { 0.58751830f, -0.76027237f},
    { 0.76027237f,  0.58751830f},
    { 0.23389032f,  0.00000000f},
    {-0.08832942f, -0.11430184f},
    { 0.00000000f,  0.00000000f},
    { 0.03516384f,  0.00000000f} }
};

// ---------------------------------------------------------------------------
// Stage 1: level-2 synthesis (Q-shift). For combo = m*2+n:
//   lo2[combo] = sfb2d(lows[m,n], butterflied(highs1), SF[m] rows, SF[n] cols)
// One thread owns (combo,b, column t, channel c, row segment), computes BOTH
// column parities (shared taps), streams rows with a 5-deep register window.
// __launch_bounds__(128,3): grid supplies exactly 3 waves/SIMD; cap VGPR at
// ~170 so the 35-load batch stays fully in flight (R3: default bound -> 60
// VGPR -> loads chunked ~10-deep -> latency-serialized).
// ---------------------------------------------------------------------------
__global__ __launch_bounds__(128, 3) void idtcwt_stage1(
    const float* __restrict__ lows, const float* __restrict__ highs1,
    float* __restrict__ lo2)
{
  constexpr int HIN = 128, WIN = 128, C = 3, B = 16;
  constexpr int ROWF  = WIN * C;        // 384 floats per input row
  constexpr int ROWO  = 2 * WIN * C;    // 768 floats per output row
  constexpr int PLANE = HIN * WIN * C;  // 49152
  constexpr int SEG   = 16;

  const int jj = blockIdx.x * 128 + threadIdx.x;  // 0..383 = (t, c)
  const int c  = jj % 3;
  const int t  = jj / 3;                // input column 0..127
  const int z  = blockIdx.z;            // combo*16 + b
  const int combo = z >> 4;
  const int b     = z & 15;
  const int m = combo >> 1, n = combo & 1;

  const float* lo = lows + (combo * B + b) * PLANE;
  // butterfly tree pair: m==n -> trees (0,0)&(1,1); else (0,1)&(1,0); sign by m
  const int pa = (m == n) ? 0 : 1;
  const int pb = (m == n) ? 3 : 2;
  const float sgn = (m == 0) ? 1.0f : -1.0f;
  const int bandStride = B * PLANE;     // 786432
  const float* hA = highs1 + (pa * 3 * B + b) * PLANE;  // band 0 base
  const float* hB = highs1 + (pb * 3 * B + b) * PLANE;

  int wc3[5];
#pragma unroll
  for (int p = 0; p < 5; ++p) {
    int w = t + 2 - p;
    if (w >= WIN) w -= WIN;
    if (w < 0)  w += WIN;
    wc3[p] = w * C + c;
  }

  float lae[5], lao[5], hae[5], hao[5];
#pragma unroll
  for (int k = 0; k < 5; ++k) { lae[k]=0.f; lao[k]=0.f; hae[k]=0.f; hao[k]=0.f; }

  const int s0 = blockIdx.y * SEG;
  float* outp = lo2 + (combo * B + b) * (4 * PLANE);  // 256*256*3 per plane

#pragma unroll 1
  for (int ui = 0; ui < SEG + 4; ++ui) {
    const int u  = (s0 - 2 + ui) & (HIN - 1);
    // slide window
#pragma unroll
    for (int k = 0; k < 4; ++k) { lae[k]=lae[k+1]; lao[k]=lao[k+1]; hae[k]=hae[k+1]; hao[k]=hao[k+1]; }
    const int rb = u * ROWF;

    // ---- batched load pass: 35 loads, all static-indexed ----
    float rl[5], rA[3][5], rB[3][5];
#pragma unroll
    for (int p = 0; p < 5; ++p) {
      const int idx = rb + wc3[p];
      rl[p]    = lo[idx];
      rA[0][p] = hA[idx];
      rB[0][p] = hB[idx];
      rA[1][p] = hA[idx +   bandStride];
      rB[1][p] = hB[idx +   bandStride];
      rA[2][p] = hA[idx + 2*bandStride];
      rB[2][p] = hB[idx + 2*bandStride];
    }

    // ---- compute pass ----
    float aLe=0.f, aLo=0.f, aHe=0.f, aHo=0.f;
#pragma unroll
    for (int p = 0; p < 5; ++p) {
      const float lv  = rl[p];
      const float lhv = (rA[0][p] + sgn * rB[0][p]) * INV_SQRT2;
      const float hlv = (rA[1][p] + sgn * rB[1][p]) * INV_SQRT2;
      const float hhv = (rA[2][p] + sgn * rB[2][p]) * INV_SQRT2;
      const float ce0 = c_qshift[n][9 - 2*p][0], ce1 = c_qshift[n][9 - 2*p][1];
      const float co0 = c_qshift[n][8 - 2*p][0], co1 = c_qshift[n][8 - 2*p][1];
      aLe += ce0 * lv  + ce1 * lhv;
      aLo += co0 * lv  + co1 * lhv;
      aHe += ce0 * hlv + ce1 * hhv;
      aHo += co0 * hlv + co1 * hhv;
    }
    lae[4]=aLe; lao[4]=aLo; hae[4]=aHe; hao[4]=aHo;

    if (ui >= 4) {
      const int s = s0 + ui - 4;
      float o00=0.f, o01=0.f, o10=0.f, o11=0.f;   // o{row parity}{col parity}
#pragma unroll
      for (int p = 0; p < 5; ++p) {
        const float f0l = c_qshift[m][9 - 2*p][0], f0h = c_qshift[m][9 - 2*p][1];
        const float f1l = c_qshift[m][8 - 2*p][0], f1h = c_qshift[m][8 - 2*p][1];
        o00 += f0l*lae[4-p] + f0h*hae[4-p];
        o01 += f0l*lao[4-p] + f0h*hao[4-p];
        o10 += f1l*lae[4-p] + f1h*hae[4-p];
        o11 += f1l*lao[4-p] + f1h*hao[4-p];
      }
      float* q = outp + (2*s) * ROWO + (2*t) * C + c;
      q[0]        = o00;
      q[C]        = o01;
      q[ROWO]     = o10;
      q[ROWO + C] = o11;
    }
  }
}

// ---------------------------------------------------------------------------
// Stage 2: level-1 synthesis (first-stage filters), all 4 combos fused.
// Row filter depends only on m, so we pre-sum the column-pass results over n:
//   LA_m(u) = sum_n colpass_n(lo2[m][n], LH_{m,n}),  HA_m analogous.
// __launch_bounds__(256,3): grid supplies exactly 3 waves/SIMD (768 blocks,
// 4 waves each, 256 CUs); cap VGPR at ~170 so the 80-load batch stays fully
// in flight. R3 evidence: default bound kept VGPR=60 -> ~10-load chunks,
// each eating ~400cy L2/L3 latency serially -> 5.5k cyc/iter wall vs ~660
// VALU cyc/iter.
// ---------------------------------------------------------------------------
__global__ __launch_bounds__(256, 3) void idtcwt_stage2(
    const float* __restrict__ lo2, const float* __restrict__ highs0,
    float* __restrict__ out)
{
  constexpr int HIN = 256, WIN = 256, C = 3, B = 16;
  constexpr int ROWF  = WIN * C;        // 768
  constexpr int ROWO  = 2 * WIN * C;    // 1536
  constexpr int PLANE = HIN * WIN * C;  // 196608
  constexpr int OPLANE = 512 * 512 * C; // 786432
  constexpr int SEG   = 16;

  const int jj = blockIdx.x * 256 + threadIdx.x;  // 0..767 = (t, c)
  const int c  = jj % 3;
  const int t  = jj / 3;               // 0..255
  const int b  = blockIdx.z;

  const float* l00 = lo2 + (0 * B + b) * PLANE;   // combo (0,0)
  const float* l01 = lo2 + (1 * B + b) * PLANE;   // (0,1)
  const float* l10 = lo2 + (2 * B + b) * PLANE;   // (1,0)
  const float* l11 = lo2 + (3 * B + b) * PLANE;   // (1,1)
  const int bandStride = B * PLANE;               // 3145728
  const float* h00 = highs0 + (0 * 3 * B + b) * PLANE;  // tree (0,0), band 0
  const float* h01 = highs0 + (1 * 3 * B + b) * PLANE;
  const float* h10 = highs0 + (2 * 3 * B + b) * PLANE;
  const float* h11 = highs0 + (3 * 3 * B + b) * PLANE;

  int wc3[5];
#pragma unroll
  for (int p = 0; p < 5; ++p) {
    int w = t + 2 - p;
    if (w >= WIN) w -= WIN;
    if (w < 0)  w += WIN;
    wc3[p] = w * C + c;
  }

  float la0e[5], la0o[5], la1e[5], la1o[5];
  float ha0e[5], ha0o[5], ha1e[5], ha1o[5];
#pragma unroll
  for (int k = 0; k < 5; ++k) {
    la0e[k]=0.f; la0o[k]=0.f; la1e[k]=0.f; la1o[k]=0.f;
    ha0e[k]=0.f; ha0o[k]=0.f; ha1e[k]=0.f; ha1o[k]=0.f;
  }

  const int s0 = blockIdx.y * SEG;
  float* outb = out + b * OPLANE;

#pragma unroll 1
  for (int ui = 0; ui < SEG + 4; ++ui) {
    const int u  = (s0 - 2 + ui) & (HIN - 1);
#pragma unroll
    for (int k = 0; k < 4; ++k) {
      la0e[k]=la0e[k+1]; la0o[k]=la0o[k+1]; la1e[k]=la1e[k+1]; la1o[k]=la1o[k+1];
      ha0e[k]=ha0e[k+1]; ha0o[k]=ha0o[k+1]; ha1e[k]=ha1e[k+1]; ha1o[k]=ha1o[k+1];
    }
    const int rb = u * ROWF;

    // ---- batched load pass: 80 loads, all static-indexed ----
    float rv[4][5];     // lo2 combos (0,0),(0,1),(1,0),(1,1)
    float rx[3][4][5];  // [band][tree 00,11,01,10][tap]
#pragma unroll
    for (int p = 0; p < 5; ++p) {
      const int idx = rb + wc3[p];
      rv[0][p] = l00[idx];
      rv[1][p] = l01[idx];
      rv[2][p] = l10[idx];
      rv[3][p] = l11[idx];
#pragma unroll
      for (int bb = 0; bb < 3; ++bb) {
        const int ib = idx + bb * bandStride;
        rx[bb][0][p] = h00[ib];
        rx[bb][1][p] = h11[ib];
        rx[bb][2][p] = h01[ib];
        rx[bb][3][p] = h10[ib];
      }
    }

    // ---- compute pass ----
    float A0e=0.f,A0o=0.f,A1e=0.f,A1o=0.f, H0e=0.f,H0o=0.f,H1e=0.f,H1o=0.f;
#pragma unroll
    for (int p = 0; p < 5; ++p) {
      const float a0e = c_first[0][9-2*p][0], a0o = c_first[0][8-2*p][0];
      const float b0e = c_first[0][9-2*p][1], b0o = c_first[0][8-2*p][1];
      const float a1e = c_first[1][9-2*p][0], a1o = c_first[1][8-2*p][0];
      const float b1e = c_first[1][9-2*p][1], b1o = c_first[1][8-2*p][1];
      { // lo2 terms: filter-n ch0, no butterfly
        const float v00=rv[0][p], v01=rv[1][p], v10=rv[2][p], v11=rv[3][p];
        A0e += a0e*v00 + a1e*v01;   A0o += a0o*v00 + a1o*v01;
        A1e += a0e*v10 + a1e*v11;   A1o += a0o*v10 + a1o*v11;
      }
      { // LH band (ch1 coeff)
        const float s1=(rx[0][0][p]+rx[0][1][p])*INV_SQRT2, d1=(rx[0][0][p]-rx[0][1][p])*INV_SQRT2;
        const float s2=(rx[0][2][p]+rx[0][3][p])*INV_SQRT2, d2=(rx[0][2][p]-rx[0][3][p])*INV_SQRT2;
        A0e += b0e*s1 + b1e*s2;   A0o += b0o*s1 + b1o*s2;
        A1e += b0e*d2 + b1e*d1;   A1o += b0o*d2 + b1o*d1;
      }
      { // HL band (ch0 coeff)
        const float s1=(rx[1][0][p]+rx[1][1][p])*INV_SQRT2, d1=(rx[1][0][p]-rx[1][1][p])*INV_SQRT2;
        const float s2=(rx[1][2][p]+rx[1][3][p])*INV_SQRT2, d2=(rx[1][2][p]-rx[1][3][p])*INV_SQRT2;
        H0e += a0e*s1 + a1e*s2;   H0o += a0o*s1 + a1o*s2;
        H1e += a0e*d2 + a1e*d1;   H1o += a0o*d2 + a1o*d1;
      }
      { // HH band (ch1 coeff)
        const float s1=(rx[2][0][p]+rx[2][1][p])*INV_SQRT2, d1=(rx[2][0][p]-rx[2][1][p])*INV_SQRT2;
        const float s2=(rx[2][2][p]+rx[2][3][p])*INV_SQRT2, d2=(rx[2][2][p]-rx[2][3][p])*INV_SQRT2;
        H0e += b0e*s1 + b1e*s2;   H0o += b0o*s1 + b1o*s2;
        H1e += b0e*d2 + b1e*d1;   H1o += b0o*d2 + b1o*d1;
      }
    }
    la0e[4]=A0e; la0o[4]=A0o; la1e[4]=A1e; la1o[4]=A1o;
    ha0e[4]=H0e; ha0o[4]=H0o; ha1e[4]=H1e; ha1o[4]=H1o;

    if (ui >= 4) {
      const int s = s0 + ui - 4;
      float o00=0.f, o01=0.f, o10=0.f, o11=0.f;   // o{row parity}{col parity}
#pragma unroll
      for (int p = 0; p < 5; ++p) {
        const float f00 = c_first[0][9-2*p][0], g00 = c_first[0][9-2*p][1]; // m=0, r=0
        const float f01 = c_first[0][8-2*p][0], g01 = c_first[0][8-2*p][1]; // m=0, r=1
        const float f10 = c_first[1][9-2*p][0], g10 = c_first[1][9-2*p][1]; // m=1, r=0
        const float f11 = c_first[1][8-2*p][0], g11 = c_first[1][8-2*p][1]; // m=1, r=1
        o00 += f00*la0e[4-p] + g00*ha0e[4-p] + f10*la1e[4-p] + g10*ha1e[4-p];
        o01 += f00*la0o[4-p] + g00*ha0o[4-p] + f10*la1o[4-p] + g10*ha1o[4-p];
        o10 += f01*la0e[4-p] + g01*ha0e[4-p] + f11*la1e[4-p] + g11*ha1e[4-p];
        o11 += f01*la0o[4-p] + g01*ha0o[4-p] + f11*la1o[4-p] + g11*ha1o[4-p];
      }
      float* q = outb + (2*s) * ROWO + (2*t) * C + c;
      q[0]        = o00 * 0.5f;
      q[C]        = o01 * 0.5f;
      q[ROWO]     = o10 * 0.5f;
      q[ROWO + C] = o11 * 0.5f;
    }
  }
}

extern "C" void kernel_launch(void* const* d_in, const int* in_sizes, int n_in,
                              void* d_out, int out_size, void* d_ws, size_t ws_size,
                              hipStream_t stream) {
  const float* highs0 = (const float*)d_in[0];  // (2,2,3,16,256,256,3)
  const float* highs1 = (const float*)d_in[1];  // (2,2,3,16,128,128,3)
  const float* lows   = (const float*)d_in[2];  // (2,2,16,128,128,3)
  float* out = (float*)d_out;                   // (16,512,512,3)
  float* lo2 = (float*)d_ws;                    // 4*16*256*256*3 floats = 50.3 MB

  // Stage 1: 384 cols/plane -> 3 blocks of 128; 8 row segments of 16; 4x16 planes
  dim3 b1(128), g1(3, 8, 64);
  hipLaunchKernelGGL(idtcwt_stage1, g1, b1, 0, stream, lows, highs1, lo2);

  // Stage 2: 768 cols -> 3 blocks of 256; 16 row segments of 16; 16 batches
  dim3 b2(256), g2(3, 16, 16);
  hipLaunchKernelGGL(idtcwt_stage2, g2, b2, 0, stream, lo2, highs0, out);
}

// Round 5
// 120.221 us; speedup vs baseline: 1.3301x; 1.3301x over previous
//
#include <hip/hip_runtime.h>

#define INV_SQRT2 0.70710678118654752440f

// Original (non-reversed) analysis filter tables, exactly as in the reference.
// The synthesis filters are the time-reversed rows; we fold the reversal into
// the index:  out[2s+r] = sum_p ORIG[9 - r - 2p][ch] * x[(s+2-p) mod n]
__constant__ float c_first[2][10][2] = {
  { { 0.00000000000000f,  0.00000000000000f},
    {-0.08838834764832f, -0.01122679215254f},
    { 0.08838834764832f,  0.01122679215254f},
    { 0.69587998903400f,  0.08838834764832f},
    { 0.69587998903400f,  0.08838834764832f},
    { 0.08838834764832f, -0.69587998903400f},
    {-0.08838834764832f,  0.69587998903400f},
    { 0.01122679215254f, -0.08838834764832f},
    { 0.01122679215254f, -0.08838834764832f},
    { 0.00000000000000f,  0.00000000000000f} },
  { { 0.01122679215254f,  0.00000000000000f},
    { 0.01122679215254f,  0.00000000000000f},
    {-0.08838834764832f, -0.08838834764832f},
    { 0.08838834764832f, -0.08838834764832f},
    { 0.69587998903400f,  0.69587998903400f},
    { 0.69587998903400f, -0.69587998903400f},
    { 0.08838834764832f,  0.08838834764832f},
    {-0.08838834764832f,  0.08838834764832f},
    { 0.00000000000000f,  0.01122679215254f},
    { 0.00000000000000f, -0.01122679215254f} }
};

__constant__ float c_qshift[2][10][2] = {
  { { 0.03516384f,  0.00000000f},
    { 0.00000000f,  0.00000000f},
    {-0.08832942f, -0.11430184f},
    { 0.23389032f,  0.00000000f},
    { 0.76027237f,  0.58751830f},
    { 0.58751830f, -0.76027237f},
    { 0.00000000f,  0.23389032f},
    {-0.11430184f,  0.08832942f},
    { 0.00000000f,  0.00000000f},
    { 0.00000000f, -0.03516384f} },
  { { 0.00000000f, -0.03516384f},
    { 0.00000000f,  0.00000000f},
    {-0.11430184f,  0.08832942f},
    { 0.00000000f,  0.23389032f},
    { 0.58751830f, -0.76027237f},
    { 0.76027237f,  0.58751830f},
    { 0.23389032f,  0.00000000f},
    {-0.08832942f, -0.11430184f},
    { 0.00000000f,  0.00000000f},
    { 0.03516384f,  0.00000000f} }
};

// ---------------------------------------------------------------------------
// Stage 1: level-2 synthesis (Q-shift) — R3 form (L3-resident inputs, ~9us).
// ---------------------------------------------------------------------------
__global__ __launch_bounds__(128) void idtcwt_stage1(
    const float* __restrict__ lows, const float* __restrict__ highs1,
    float* __restrict__ lo2)
{
  constexpr int HIN = 128, WIN = 128, C = 3, B = 16;
  constexpr int ROWF  = WIN * C;        // 384 floats per input row
  constexpr int ROWO  = 2 * WIN * C;    // 768 floats per output row
  constexpr int PLANE = HIN * WIN * C;  // 49152
  constexpr int SEG   = 16;

  const int jj = blockIdx.x * 128 + threadIdx.x;  // 0..383 = (t, c)
  const int c  = jj % 3;
  const int t  = jj / 3;                // input column 0..127
  const int z  = blockIdx.z;            // combo*16 + b
  const int combo = z >> 4;
  const int b     = z & 15;
  const int m = combo >> 1, n = combo & 1;

  const float* lo = lows + (combo * B + b) * PLANE;
  const int pa = (m == n) ? 0 : 1;
  const int pb = (m == n) ? 3 : 2;
  const float sgn = (m == 0) ? 1.0f : -1.0f;
  const int bandStride = B * PLANE;     // 786432
  const float* hA = highs1 + (pa * 3 * B + b) * PLANE;
  const float* hB = highs1 + (pb * 3 * B + b) * PLANE;

  int wc3[5];
#pragma unroll
  for (int p = 0; p < 5; ++p) {
    int w = t + 2 - p;
    if (w >= WIN) w -= WIN;
    if (w < 0)  w += WIN;
    wc3[p] = w * C + c;
  }

  float lae[5], lao[5], hae[5], hao[5];
#pragma unroll
  for (int k = 0; k < 5; ++k) { lae[k]=0.f; lao[k]=0.f; hae[k]=0.f; hao[k]=0.f; }

  const int s0 = blockIdx.y * SEG;
  float* outp = lo2 + (combo * B + b) * (4 * PLANE);

#pragma unroll 1
  for (int ui = 0; ui < SEG + 4; ++ui) {
    const int u  = (s0 - 2 + ui) & (HIN - 1);
#pragma unroll
    for (int k = 0; k < 4; ++k) { lae[k]=lae[k+1]; lao[k]=lao[k+1]; hae[k]=hae[k+1]; hao[k]=hao[k+1]; }
    const int rb = u * ROWF;

    float rl[5], rA[3][5], rB[3][5];
#pragma unroll
    for (int p = 0; p < 5; ++p) {
      const int idx = rb + wc3[p];
      rl[p]    = lo[idx];
      rA[0][p] = hA[idx];
      rB[0][p] = hB[idx];
      rA[1][p] = hA[idx +   bandStride];
      rB[1][p] = hB[idx +   bandStride];
      rA[2][p] = hA[idx + 2*bandStride];
      rB[2][p] = hB[idx + 2*bandStride];
    }

    float aLe=0.f, aLo=0.f, aHe=0.f, aHo=0.f;
#pragma unroll
    for (int p = 0; p < 5; ++p) {
      const float lv  = rl[p];
      const float lhv = (rA[0][p] + sgn * rB[0][p]) * INV_SQRT2;
      const float hlv = (rA[1][p] + sgn * rB[1][p]) * INV_SQRT2;
      const float hhv = (rA[2][p] + sgn * rB[2][p]) * INV_SQRT2;
      const float ce0 = c_qshift[n][9 - 2*p][0], ce1 = c_qshift[n][9 - 2*p][1];
      const float co0 = c_qshift[n][8 - 2*p][0], co1 = c_qshift[n][8 - 2*p][1];
      aLe += ce0 * lv  + ce1 * lhv;
      aLo += co0 * lv  + co1 * lhv;
      aHe += ce0 * hlv + ce1 * hhv;
      aHo += co0 * hlv + co1 * hhv;
    }
    lae[4]=aLe; lao[4]=aLo; hae[4]=aHe; hao[4]=aHo;

    if (ui >= 4) {
      const int s = s0 + ui - 4;
      float o00=0.f, o01=0.f, o10=0.f, o11=0.f;
#pragma unroll
      for (int p = 0; p < 5; ++p) {
        const float f0l = c_qshift[m][9 - 2*p][0], f0h = c_qshift[m][9 - 2*p][1];
        const float f1l = c_qshift[m][8 - 2*p][0], f1h = c_qshift[m][8 - 2*p][1];
        o00 += f0l*lae[4-p] + f0h*hae[4-p];
        o01 += f0l*lao[4-p] + f0h*hao[4-p];
        o10 += f1l*lae[4-p] + f1h*hae[4-p];
        o11 += f1l*lao[4-p] + f1h*hao[4-p];
      }
      float* q = outp + (2*s) * ROWO + (2*t) * C + c;
      q[0]        = o00;
      q[C]        = o01;
      q[ROWO]     = o10;
      q[ROWO + C] = o11;
    }
  }
}

// ---------------------------------------------------------------------------
// Stage 2: level-1 synthesis, LDS row-staged (T14 async-STAGE).
// Key identity: tap p for lane jj reads global position jj + 6 - 3p of the
// same row. So each thread stages ONE float per array (coalesced), and taps
// become ds_read at [tid + imm] with compile-time offsets (2-way bank alias
// = free). Double-buffered LDS; next row's 16 global loads issued BEFORE the
// compute phase (sched_barrier pins them) so HBM latency hides under compute.
// This replaces 80 gather-loads + 64-bit addr math per iter (R3/R4: compiler
// refused to keep them in flight -> ~5.5k cyc/iter latency-serialized).
// ---------------------------------------------------------------------------
__global__ __launch_bounds__(256, 3) void idtcwt_stage2(
    const float* __restrict__ lo2, const float* __restrict__ highs0,
    float* __restrict__ out)
{
  constexpr int HIN = 256, WIN = 256, C = 3, B = 16;
  constexpr int ROWF  = WIN * C;        // 768 floats per input row
  constexpr int ROWO  = 2 * WIN * C;    // 1536
  constexpr int PLANE = HIN * WIN * C;  // 196608
  constexpr int OPLANE = 512 * 512 * C; // 786432
  constexpr int SEG   = 16;
  constexpr int NI    = SEG + 4;        // 20 iterations
  constexpr int APITCH = 272;           // dwords per array slice (268 used)
  constexpr int BUF    = 16 * APITCH;   // 4352 dwords per buffer

  __shared__ float lds[2 * BUF];        // 34816 B

  const int tid = threadIdx.x;
  const int jj  = blockIdx.x * 256 + tid;  // 0..767 = (t,c); c=jj%3, t=jj/3
  const int c   = jj % 3;
  const int t   = jj / 3;
  const int b   = blockIdx.z;

  // 16 array base pointers (all wave-uniform -> SGPR)
  const int bandStride = B * PLANE;
  const float* a0  = lo2 + (0 * B + b) * PLANE;           // l00
  const float* a1  = lo2 + (1 * B + b) * PLANE;           // l01
  const float* a2  = lo2 + (2 * B + b) * PLANE;           // l10
  const float* a3  = lo2 + (3 * B + b) * PLANE;           // l11
  const float* h00 = highs0 + (0 * 3 * B + b) * PLANE;
  const float* h01 = highs0 + (1 * 3 * B + b) * PLANE;
  const float* h10 = highs0 + (2 * 3 * B + b) * PLANE;
  const float* h11 = highs0 + (3 * 3 * B + b) * PLANE;

  // staging source lane offsets (slot k maps to global jj' = 256X - 6 + k)
  int j1 = jj - 6;  if (j1 < 0)   j1 += ROWF;   // slot tid
  int j2 = jj + 250; if (j2 >= ROWF) j2 -= ROWF; // slot 256+tid (tid<12 only)
  const bool halo = (tid < 12);

  float la0e[5], la0o[5], la1e[5], la1o[5];
  float ha0e[5], ha0o[5], ha1e[5], ha1o[5];
#pragma unroll
  for (int k = 0; k < 5; ++k) {
    la0e[k]=0.f; la0o[k]=0.f; la1e[k]=0.f; la1o[k]=0.f;
    ha0e[k]=0.f; ha0o[k]=0.f; ha1e[k]=0.f; ha1o[k]=0.f;
  }

  const int s0 = blockIdx.y * SEG;
  float* outb = out + b * OPLANE;

  // ---- staging helpers (array order: 0..3 lo2; 4+bb*4+{h00,h11,h01,h10}) ----
  float rg[16], rh[16];
#define S2_LOAD(UI)                                                          \
  {                                                                          \
    const int rb_ = ((s0 - 2 + (UI)) & (HIN - 1)) * ROWF;                    \
    rg[0] = a0[rb_ + j1]; rg[1] = a1[rb_ + j1];                              \
    rg[2] = a2[rb_ + j1]; rg[3] = a3[rb_ + j1];                              \
    rg[4]  = h00[rb_ + j1];                rg[5]  = h11[rb_ + j1];           \
    rg[6]  = h01[rb_ + j1];                rg[7]  = h10[rb_ + j1];           \
    rg[8]  = h00[rb_ + j1 + bandStride];   rg[9]  = h11[rb_ + j1 + bandStride]; \
    rg[10] = h01[rb_ + j1 + bandStride];   rg[11] = h10[rb_ + j1 + bandStride]; \
    rg[12] = h00[rb_ + j1 + 2*bandStride]; rg[13] = h11[rb_ + j1 + 2*bandStride]; \
    rg[14] = h01[rb_ + j1 + 2*bandStride]; rg[15] = h10[rb_ + j1 + 2*bandStride]; \
    if (halo) {                                                              \
      rh[0] = a0[rb_ + j2]; rh[1] = a1[rb_ + j2];                            \
      rh[2] = a2[rb_ + j2]; rh[3] = a3[rb_ + j2];                            \
      rh[4]  = h00[rb_ + j2];                rh[5]  = h11[rb_ + j2];         \
      rh[6]  = h01[rb_ + j2];                rh[7]  = h10[rb_ + j2];         \
      rh[8]  = h00[rb_ + j2 + bandStride];   rh[9]  = h11[rb_ + j2 + bandStride]; \
      rh[10] = h01[rb_ + j2 + bandStride];   rh[11] = h10[rb_ + j2 + bandStride]; \
      rh[12] = h00[rb_ + j2 + 2*bandStride]; rh[13] = h11[rb_ + j2 + 2*bandStride]; \
      rh[14] = h01[rb_ + j2 + 2*bandStride]; rh[15] = h10[rb_ + j2 + 2*bandStride]; \
    }                                                                        \
  }

#define S2_WRITE(PB)                                                         \
  {                                                                          \
    float* w_ = &lds[(PB) * BUF];                                            \
    _Pragma("unroll")                                                        \
    for (int a_ = 0; a_ < 16; ++a_) w_[a_ * APITCH + tid] = rg[a_];          \
    if (halo) {                                                              \
      _Pragma("unroll")                                                      \
      for (int a_ = 0; a_ < 16; ++a_) w_[a_ * APITCH + 256 + tid] = rh[a_];  \
    }                                                                        \
  }

  // ---- prologue: stage row for ui=0 ----
  S2_LOAD(0);
  S2_WRITE(0);
  __syncthreads();
  int pb = 0;

#pragma unroll 1
  for (int ui = 0; ui < NI; ++ui) {
    // issue next row's global loads FIRST; latency hides under compute
    if (ui + 1 < NI) {
      S2_LOAD(ui + 1);
      __builtin_amdgcn_sched_barrier(0);  // keep loads above the compute
    }

    // slide row windows
#pragma unroll
    for (int k = 0; k < 4; ++k) {
      la0e[k]=la0e[k+1]; la0o[k]=la0o[k+1]; la1e[k]=la1e[k+1]; la1o[k]=la1o[k+1];
      ha0e[k]=ha0e[k+1]; ha0o[k]=ha0o[k+1]; ha1e[k]=ha1e[k+1]; ha1o[k]=ha1o[k+1];
    }

    // ---- compute from LDS buffer pb: taps at slot tid + 12 - 3p ----
    const float* Lb = &lds[pb * BUF];
    float A0e=0.f,A0o=0.f,A1e=0.f,A1o=0.f, H0e=0.f,H0o=0.f,H1e=0.f,H1o=0.f;
#pragma unroll
    for (int p = 0; p < 5; ++p) {
      const int sl = tid + (12 - 3*p);
      const float a0e = c_first[0][9-2*p][0], a0o = c_first[0][8-2*p][0];
      const float b0e = c_first[0][9-2*p][1], b0o = c_first[0][8-2*p][1];
      const float a1e = c_first[1][9-2*p][0], a1o = c_first[1][8-2*p][0];
      const float b1e = c_first[1][9-2*p][1], b1o = c_first[1][8-2*p][1];
      { // lo2 terms
        const float v00=Lb[0*APITCH+sl], v01=Lb[1*APITCH+sl];
        const float v10=Lb[2*APITCH+sl], v11=Lb[3*APITCH+sl];
        A0e += a0e*v00 + a1e*v01;   A0o += a0o*v00 + a1o*v01;
        A1e += a0e*v10 + a1e*v11;   A1o += a0o*v10 + a1o*v11;
      }
      { // LH band (ch1 coeff)
        const float x00=Lb[4*APITCH+sl], x11=Lb[5*APITCH+sl];
        const float x01=Lb[6*APITCH+sl], x10=Lb[7*APITCH+sl];
        const float s1=(x00+x11)*INV_SQRT2, d1=(x00-x11)*INV_SQRT2;
        const float s2=(x01+x10)*INV_SQRT2, d2=(x01-x10)*INV_SQRT2;
        A0e += b0e*s1 + b1e*s2;   A0o += b0o*s1 + b1o*s2;
        A1e += b0e*d2 + b1e*d1;   A1o += b0o*d2 + b1o*d1;
      }
      { // HL band (ch0 coeff)
        const float x00=Lb[8*APITCH+sl], x11=Lb[9*APITCH+sl];
        const float x01=Lb[10*APITCH+sl], x10=Lb[11*APITCH+sl];
        const float s1=(x00+x11)*INV_SQRT2, d1=(x00-x11)*INV_SQRT2;
        const float s2=(x01+x10)*INV_SQRT2, d2=(x01-x10)*INV_SQRT2;
        H0e += a0e*s1 + a1e*s2;   H0o += a0o*s1 + a1o*s2;
        H1e += a0e*d2 + a1e*d1;   H1o += a0o*d2 + a1o*d1;
      }
      { // HH band (ch1 coeff)
        const float x00=Lb[12*APITCH+sl], x11=Lb[13*APITCH+sl];
        const float x01=Lb[14*APITCH+sl], x10=Lb[15*APITCH+sl];
        const float s1=(x00+x11)*INV_SQRT2, d1=(x00-x11)*INV_SQRT2;
        const float s2=(x01+x10)*INV_SQRT2, d2=(x01-x10)*INV_SQRT2;
        H0e += b0e*s1 + b1e*s2;   H0o += b0o*s1 + b1o*s2;
        H1e += b0e*d2 + b1e*d1;   H1o += b0o*d2 + b1o*d1;
      }
    }
    la0e[4]=A0e; la0o[4]=A0o; la1e[4]=A1e; la1o[4]=A1o;
    ha0e[4]=H0e; ha0o[4]=H0o; ha1e[4]=H1e; ha1o[4]=H1o;

    if (ui >= 4) {
      const int s = s0 + ui - 4;
      float o00=0.f, o01=0.f, o10=0.f, o11=0.f;
#pragma unroll
      for (int p = 0; p < 5; ++p) {
        const float f00 = c_first[0][9-2*p][0], g00 = c_first[0][9-2*p][1];
        const float f01 = c_first[0][8-2*p][0], g01 = c_first[0][8-2*p][1];
        const float f10 = c_first[1][9-2*p][0], g10 = c_first[1][9-2*p][1];
        const float f11 = c_first[1][8-2*p][0], g11 = c_first[1][8-2*p][1];
        o00 += f00*la0e[4-p] + g00*ha0e[4-p] + f10*la1e[4-p] + g10*ha1e[4-p];
        o01 += f00*la0o[4-p] + g00*ha0o[4-p] + f10*la1o[4-p] + g10*ha1o[4-p];
        o10 += f01*la0e[4-p] + g01*ha0e[4-p] + f11*la1e[4-p] + g11*ha1e[4-p];
        o11 += f01*la0o[4-p] + g01*ha0o[4-p] + f11*la1o[4-p] + g11*ha1o[4-p];
      }
      float* q = outb + (2*s) * ROWO + (2*t) * C + c;
      q[0]        = o00 * 0.5f;
      q[C]        = o01 * 0.5f;
      q[ROWO]     = o10 * 0.5f;
      q[ROWO + C] = o11 * 0.5f;
    }

    // stage next row into the other buffer (vmcnt wait lands here), then sync
    if (ui + 1 < NI) {
      S2_WRITE(pb ^ 1);
    }
    __syncthreads();
    pb ^= 1;
  }
#undef S2_LOAD
#undef S2_WRITE
}

extern "C" void kernel_launch(void* const* d_in, const int* in_sizes, int n_in,
                              void* d_out, int out_size, void* d_ws, size_t ws_size,
                              hipStream_t stream) {
  const float* highs0 = (const float*)d_in[0];  // (2,2,3,16,256,256,3)
  const float* highs1 = (const float*)d_in[1];  // (2,2,3,16,128,128,3)
  const float* lows   = (const float*)d_in[2];  // (2,2,16,128,128,3)
  float* out = (float*)d_out;                   // (16,512,512,3)
  float* lo2 = (float*)d_ws;                    // 4*16*256*256*3 floats = 50.3 MB

  // Stage 1: 384 cols/plane -> 3 blocks of 128; 8 row segments of 16; 4x16 planes
  dim3 b1(128), g1(3, 8, 64);
  hipLaunchKernelGGL(idtcwt_stage1, g1, b1, 0, stream, lows, highs1, lo2);

  // Stage 2: 768 jj -> 3 blocks of 256; 16 row segments of 16; 16 batches
  dim3 b2(256), g2(3, 16, 16);
  hipLaunchKernelGGL(idtcwt_stage2, g2, b2, 0, stream, lo2, highs0, out);
}

// Round 6
// 112.355 us; speedup vs baseline: 1.4232x; 1.0700x over previous
//
#include <hip/hip_runtime.h>

#define INV_SQRT2 0.70710678118654752440f

// Original (non-reversed) analysis filter tables, exactly as in the reference.
// The synthesis filters are the time-reversed rows; we fold the reversal into
// the index:  out[2s+r] = sum_p ORIG[9 - r - 2p][ch] * x[(s+2-p) mod n]
__constant__ float c_first[2][10][2] = {
  { { 0.00000000000000f,  0.00000000000000f},
    {-0.08838834764832f, -0.01122679215254f},
    { 0.08838834764832f,  0.01122679215254f},
    { 0.69587998903400f,  0.08838834764832f},
    { 0.69587998903400f,  0.08838834764832f},
    { 0.08838834764832f, -0.69587998903400f},
    {-0.08838834764832f,  0.69587998903400f},
    { 0.01122679215254f, -0.08838834764832f},
    { 0.01122679215254f, -0.08838834764832f},
    { 0.00000000000000f,  0.00000000000000f} },
  { { 0.01122679215254f,  0.00000000000000f},
    { 0.01122679215254f,  0.00000000000000f},
    {-0.08838834764832f, -0.08838834764832f},
    { 0.08838834764832f, -0.08838834764832f},
    { 0.69587998903400f,  0.69587998903400f},
    { 0.69587998903400f, -0.69587998903400f},
    { 0.08838834764832f,  0.08838834764832f},
    {-0.08838834764832f,  0.08838834764832f},
    { 0.00000000000000f,  0.01122679215254f},
    { 0.00000000000000f, -0.01122679215254f} }
};

__constant__ float c_qshift[2][10][2] = {
  { { 0.03516384f,  0.00000000f},
    { 0.00000000f,  0.00000000f},
    {-0.08832942f, -0.11430184f},
    { 0.23389032f,  0.00000000f},
    { 0.76027237f,  0.58751830f},
    { 0.58751830f, -0.76027237f},
    { 0.00000000f,  0.23389032f},
    {-0.11430184f,  0.08832942f},
    { 0.00000000f,  0.00000000f},
    { 0.00000000f, -0.03516384f} },
  { { 0.00000000f, -0.03516384f},
    { 0.00000000f,  0.00000000f},
    {-0.11430184f,  0.08832942f},
    { 0.00000000f,  0.23389032f},
    { 0.58751830f, -0.76027237f},
    { 0.76027237f,  0.58751830f},
    { 0.23389032f,  0.00000000f},
    {-0.08832942f, -0.11430184f},
    { 0.00000000f,  0.00000000f},
    { 0.03516384f,  0.00000000f} }
};

// ---------------------------------------------------------------------------
// Stage 1: level-2 synthesis (Q-shift) — R3 form (L3-resident inputs, ~9us).
// ---------------------------------------------------------------------------
__global__ __launch_bounds__(128) void idtcwt_stage1(
    const float* __restrict__ lows, const float* __restrict__ highs1,
    float* __restrict__ lo2)
{
  constexpr int HIN = 128, WIN = 128, C = 3, B = 16;
  constexpr int ROWF  = WIN * C;        // 384 floats per input row
  constexpr int ROWO  = 2 * WIN * C;    // 768 floats per output row
  constexpr int PLANE = HIN * WIN * C;  // 49152
  constexpr int SEG   = 16;

  const int jj = blockIdx.x * 128 + threadIdx.x;  // 0..383 = (t, c)
  const int c  = jj % 3;
  const int t  = jj / 3;                // input column 0..127
  const int z  = blockIdx.z;            // combo*16 + b
  const int combo = z >> 4;
  const int b     = z & 15;
  const int m = combo >> 1, n = combo & 1;

  const float* lo = lows + (combo * B + b) * PLANE;
  const int pa = (m == n) ? 0 : 1;
  const int pb = (m == n) ? 3 : 2;
  const float sgn = (m == 0) ? 1.0f : -1.0f;
  const int bandStride = B * PLANE;     // 786432
  const float* hA = highs1 + (pa * 3 * B + b) * PLANE;
  const float* hB = highs1 + (pb * 3 * B + b) * PLANE;

  int wc3[5];
#pragma unroll
  for (int p = 0; p < 5; ++p) {
    int w = t + 2 - p;
    if (w >= WIN) w -= WIN;
    if (w < 0)  w += WIN;
    wc3[p] = w * C + c;
  }

  float lae[5], lao[5], hae[5], hao[5];
#pragma unroll
  for (int k = 0; k < 5; ++k) { lae[k]=0.f; lao[k]=0.f; hae[k]=0.f; hao[k]=0.f; }

  const int s0 = blockIdx.y * SEG;
  float* outp = lo2 + (combo * B + b) * (4 * PLANE);

#pragma unroll 1
  for (int ui = 0; ui < SEG + 4; ++ui) {
    const int u  = (s0 - 2 + ui) & (HIN - 1);
#pragma unroll
    for (int k = 0; k < 4; ++k) { lae[k]=lae[k+1]; lao[k]=lao[k+1]; hae[k]=hae[k+1]; hao[k]=hao[k+1]; }
    const int rb = u * ROWF;

    float rl[5], rA[3][5], rB[3][5];
#pragma unroll
    for (int p = 0; p < 5; ++p) {
      const int idx = rb + wc3[p];
      rl[p]    = lo[idx];
      rA[0][p] = hA[idx];
      rB[0][p] = hB[idx];
      rA[1][p] = hA[idx +   bandStride];
      rB[1][p] = hB[idx +   bandStride];
      rA[2][p] = hA[idx + 2*bandStride];
      rB[2][p] = hB[idx + 2*bandStride];
    }

    float aLe=0.f, aLo=0.f, aHe=0.f, aHo=0.f;
#pragma unroll
    for (int p = 0; p < 5; ++p) {
      const float lv  = rl[p];
      const float lhv = (rA[0][p] + sgn * rB[0][p]) * INV_SQRT2;
      const float hlv = (rA[1][p] + sgn * rB[1][p]) * INV_SQRT2;
      const float hhv = (rA[2][p] + sgn * rB[2][p]) * INV_SQRT2;
      const float ce0 = c_qshift[n][9 - 2*p][0], ce1 = c_qshift[n][9 - 2*p][1];
      const float co0 = c_qshift[n][8 - 2*p][0], co1 = c_qshift[n][8 - 2*p][1];
      aLe += ce0 * lv  + ce1 * lhv;
      aLo += co0 * lv  + co1 * lhv;
      aHe += ce0 * hlv + ce1 * hhv;
      aHo += co0 * hlv + co1 * hhv;
    }
    lae[4]=aLe; lao[4]=aLo; hae[4]=aHe; hao[4]=aHo;

    if (ui >= 4) {
      const int s = s0 + ui - 4;
      float o00=0.f, o01=0.f, o10=0.f, o11=0.f;
#pragma unroll
      for (int p = 0; p < 5; ++p) {
        const float f0l = c_qshift[m][9 - 2*p][0], f0h = c_qshift[m][9 - 2*p][1];
        const float f1l = c_qshift[m][8 - 2*p][0], f1h = c_qshift[m][8 - 2*p][1];
        o00 += f0l*lae[4-p] + f0h*hae[4-p];
        o01 += f0l*lao[4-p] + f0h*hao[4-p];
        o10 += f1l*lae[4-p] + f1h*hae[4-p];
        o11 += f1l*lao[4-p] + f1h*hao[4-p];
      }
      float* q = outp + (2*s) * ROWO + (2*t) * C + c;
      q[0]        = o00;
      q[C]        = o01;
      q[ROWO]     = o10;
      q[ROWO + C] = o11;
    }
  }
}

// ---------------------------------------------------------------------------
// Stage 2: level-1 synthesis, LDS row-staged, WIDE ds ops + circular window.
// R6 changes vs R5 (91us: LDS pipe ~61% busy on 96 scalar ds ops/iter, VALU
// 54% incl. 80 LDS addrs + 64 window movs):
//  - LDS layout [slot][16 arrays @ pitch 20 floats]: stage = 4 ds_write_b128,
//    tap = 4 ds_read_b128 (arrays grouped exactly as consumed). Pitch 20
//    (80B): lanes start at banks (l*20)%32 = 8 groups x 4 consecutive banks
//    tiling all 32 -> conflict-free. 96 scalar ds ops -> 24 wide.
//  - unroll-by-5 circular window: w[k] / w[(k-p)%5] all static -> no movs.
// ---------------------------------------------------------------------------
__global__ __launch_bounds__(256, 3) void idtcwt_stage2(
    const float* __restrict__ lo2, const float* __restrict__ highs0,
    float* __restrict__ out)
{
  constexpr int HIN = 256, WIN = 256, C = 3, B = 16;
  constexpr int ROWF  = WIN * C;        // 768 floats per input row
  constexpr int ROWO  = 2 * WIN * C;    // 1536
  constexpr int PLANE = HIN * WIN * C;  // 196608
  constexpr int OPLANE = 512 * 512 * C; // 786432
  constexpr int SEG   = 16;
  constexpr int NI    = SEG + 4;        // 20 iterations
  constexpr int PITCH = 5;              // float4s per slot (16 arrays + pad)
  constexpr int BUFV4 = 272 * PITCH;    // 1360 float4 per buffer

  __shared__ float4 lds4[2 * BUFV4];    // 43,520 B -> 3 blocks/CU

  const int tid = threadIdx.x;
  const int jj  = blockIdx.x * 256 + tid;  // 0..767 = (t,c)
  const int c   = jj % 3;
  const int t   = jj / 3;
  const int b   = blockIdx.z;

  const int bandStride = B * PLANE;
  const float* a0  = lo2 + (0 * B + b) * PLANE;           // l00
  const float* a1  = lo2 + (1 * B + b) * PLANE;           // l01
  const float* a2  = lo2 + (2 * B + b) * PLANE;           // l10
  const float* a3  = lo2 + (3 * B + b) * PLANE;           // l11
  const float* h00b0 = highs0 + (0 * 3 * B + b) * PLANE;
  const float* h01b0 = highs0 + (1 * 3 * B + b) * PLANE;
  const float* h10b0 = highs0 + (2 * 3 * B + b) * PLANE;
  const float* h11b0 = highs0 + (3 * 3 * B + b) * PLANE;
  const float* h00b1 = h00b0 + bandStride;
  const float* h01b1 = h01b0 + bandStride;
  const float* h10b1 = h10b0 + bandStride;
  const float* h11b1 = h11b0 + bandStride;
  const float* h00b2 = h00b0 + 2*bandStride;
  const float* h01b2 = h01b0 + 2*bandStride;
  const float* h10b2 = h10b0 + 2*bandStride;
  const float* h11b2 = h11b0 + 2*bandStride;

  // staging source offsets (slot k holds global jj' = 256*blockIdx.x - 6 + k)
  int j1 = jj - 6;   if (j1 < 0)     j1 += ROWF;   // slot tid
  int j2 = jj + 250; if (j2 >= ROWF) j2 -= ROWF;   // slot 256+tid (tid<12)
  const bool halo = (tid < 12);

  // circular window, all indices static after unroll
  float wla0e[5], wla0o[5], wla1e[5], wla1o[5];
  float wha0e[5], wha0o[5], wha1e[5], wha1o[5];

  const int s0 = blockIdx.y * SEG;
  float* outb = out + b * OPLANE;

  float4 G0, G1, G2, G3, Hh0, Hh1, Hh2, Hh3;

#define S2_LOAD(I)                                                           \
  {                                                                          \
    const int rb_ = ((s0 - 2 + (I)) & (HIN - 1)) * ROWF;                     \
    const int o1_ = rb_ + j1;                                                \
    G0 = make_float4(a0[o1_], a1[o1_], a2[o1_], a3[o1_]);                    \
    G1 = make_float4(h00b0[o1_], h11b0[o1_], h01b0[o1_], h10b0[o1_]);        \
    G2 = make_float4(h00b1[o1_], h11b1[o1_], h01b1[o1_], h10b1[o1_]);        \
    G3 = make_float4(h00b2[o1_], h11b2[o1_], h01b2[o1_], h10b2[o1_]);        \
    if (halo) {                                                              \
      const int o2_ = rb_ + j2;                                              \
      Hh0 = make_float4(a0[o2_], a1[o2_], a2[o2_], a3[o2_]);                 \
      Hh1 = make_float4(h00b0[o2_], h11b0[o2_], h01b0[o2_], h10b0[o2_]);     \
      Hh2 = make_float4(h00b1[o2_], h11b1[o2_], h01b1[o2_], h10b1[o2_]);     \
      Hh3 = make_float4(h00b2[o2_], h11b2[o2_], h01b2[o2_], h10b2[o2_]);     \
    }                                                                        \
  }

#define S2_WRITE(DST)                                                        \
  {                                                                          \
    float4* w_ = (DST) + tid * PITCH;                                        \
    w_[0] = G0; w_[1] = G1; w_[2] = G2; w_[3] = G3;                          \
    if (halo) {                                                              \
      float4* w2_ = (DST) + (256 + tid) * PITCH;                             \
      w2_[0] = Hh0; w2_[1] = Hh1; w2_[2] = Hh2; w2_[3] = Hh3;                \
    }                                                                        \
  }

  float4* cur = lds4;
  float4* nxt = lds4 + BUFV4;

  // ---- prologue: stage row i=0 ----
  S2_LOAD(0);
  S2_WRITE(cur);
  __syncthreads();

#pragma unroll 1
  for (int uo = 0; uo < 4; ++uo) {
#pragma unroll
    for (int k = 0; k < 5; ++k) {
      const int i = uo * 5 + k;           // window slot = k (static)

      if (i < NI - 1) {
        S2_LOAD(i + 1);
        __builtin_amdgcn_sched_barrier(0);  // keep loads above the compute
      }

      // ---- column pass from cur: taps at slot tid + 12 - 3p ----
      float A0e=0.f,A0o=0.f,A1e=0.f,A1o=0.f, H0e=0.f,H0o=0.f,H1e=0.f,H1o=0.f;
#pragma unroll
      for (int p = 0; p < 5; ++p) {
        const float4* qp = cur + (tid + (12 - 3*p)) * PITCH;
        const float4 q0 = qp[0], q1 = qp[1], q2 = qp[2], q3 = qp[3];
        const float a0e = c_first[0][9-2*p][0], a0o = c_first[0][8-2*p][0];
        const float b0e = c_first[0][9-2*p][1], b0o = c_first[0][8-2*p][1];
        const float a1e = c_first[1][9-2*p][0], a1o = c_first[1][8-2*p][0];
        const float b1e = c_first[1][9-2*p][1], b1o = c_first[1][8-2*p][1];
        { // lo2 terms
          A0e += a0e*q0.x + a1e*q0.y;   A0o += a0o*q0.x + a1o*q0.y;
          A1e += a0e*q0.z + a1e*q0.w;   A1o += a0o*q0.z + a1o*q0.w;
        }
        { // LH band (ch1 coeff): q1 = (h00, h11, h01, h10)
          const float s1=(q1.x+q1.y)*INV_SQRT2, d1=(q1.x-q1.y)*INV_SQRT2;
          const float s2=(q1.z+q1.w)*INV_SQRT2, d2=(q1.z-q1.w)*INV_SQRT2;
          A0e += b0e*s1 + b1e*s2;   A0o += b0o*s1 + b1o*s2;
          A1e += b0e*d2 + b1e*d1;   A1o += b0o*d2 + b1o*d1;
        }
        { // HL band (ch0 coeff)
          const float s1=(q2.x+q2.y)*INV_SQRT2, d1=(q2.x-q2.y)*INV_SQRT2;
          const float s2=(q2.z+q2.w)*INV_SQRT2, d2=(q2.z-q2.w)*INV_SQRT2;
          H0e += a0e*s1 + a1e*s2;   H0o += a0o*s1 + a1o*s2;
          H1e += a0e*d2 + a1e*d1;   H1o += a0o*d2 + a1o*d1;
        }
        { // HH band (ch1 coeff)
          const float s1=(q3.x+q3.y)*INV_SQRT2, d1=(q3.x-q3.y)*INV_SQRT2;
          const float s2=(q3.z+q3.w)*INV_SQRT2, d2=(q3.z-q3.w)*INV_SQRT2;
          H0e += b0e*s1 + b1e*s2;   H0o += b0o*s1 + b1o*s2;
          H1e += b0e*d2 + b1e*d1;   H1o += b0o*d2 + b1o*d1;
        }
      }
      wla0e[k]=A0e; wla0o[k]=A0o; wla1e[k]=A1e; wla1o[k]=A1o;
      wha0e[k]=H0e; wha0o[k]=H0o; wha1e[k]=H1e; wha1o[k]=H1o;

      if (i >= 4) {
        const int s = s0 + i - 4;
        float o00=0.f, o01=0.f, o10=0.f, o11=0.f;
#pragma unroll
        for (int p = 0; p < 5; ++p) {
          const int kk = (k - p + 5) % 5;   // static
          const float f00 = c_first[0][9-2*p][0], g00 = c_first[0][9-2*p][1];
          const float f01 = c_first[0][8-2*p][0], g01 = c_first[0][8-2*p][1];
          const float f10 = c_first[1][9-2*p][0], g10 = c_first[1][9-2*p][1];
          const float f11 = c_first[1][8-2*p][0], g11 = c_first[1][8-2*p][1];
          o00 += f00*wla0e[kk] + g00*wha0e[kk] + f10*wla1e[kk] + g10*wha1e[kk];
          o01 += f00*wla0o[kk] + g00*wha0o[kk] + f10*wla1o[kk] + g10*wha1o[kk];
          o10 += f01*wla0e[kk] + g01*wha0e[kk] + f11*wla1e[kk] + g11*wha1e[kk];
          o11 += f01*wla0o[kk] + g01*wha0o[kk] + f11*wla1o[kk] + g11*wha1o[kk];
        }
        float* q = outb + (2*s) * ROWO + (2*t) * C + c;
        q[0]        = o00 * 0.5f;
        q[C]        = o01 * 0.5f;
        q[ROWO]     = o10 * 0.5f;
        q[ROWO + C] = o11 * 0.5f;
      }

      if (i < NI - 1) {
        S2_WRITE(nxt);                    // vmcnt wait lands here
      }
      __syncthreads();
      { float4* tmp = cur; cur = nxt; nxt = tmp; }
    }
  }
#undef S2_LOAD
#undef S2_WRITE
}

extern "C" void kernel_launch(void* const* d_in, const int* in_sizes, int n_in,
                              void* d_out, int out_size, void* d_ws, size_t ws_size,
                              hipStream_t stream) {
  const float* highs0 = (const float*)d_in[0];  // (2,2,3,16,256,256,3)
  const float* highs1 = (const float*)d_in[1];  // (2,2,3,16,128,128,3)
  const float* lows   = (const float*)d_in[2];  // (2,2,16,128,128,3)
  float* out = (float*)d_out;                   // (16,512,512,3)
  float* lo2 = (float*)d_ws;                    // 4*16*256*256*3 floats = 50.3 MB

  // Stage 1: 384 cols/plane -> 3 blocks of 128; 8 row segments of 16; 4x16 planes
  dim3 b1(128), g1(3, 8, 64);
  hipLaunchKernelGGL(idtcwt_stage1, g1, b1, 0, stream, lows, highs1, lo2);

  // Stage 2: 768 jj -> 3 blocks of 256; 16 row segments of 16; 16 batches
  dim3 b2(256), g2(3, 16, 16);
  hipLaunchKernelGGL(idtcwt_stage2, g2, b2, 0, stream, lo2, highs0, out);
}